// Round 7
// baseline (305.539 us; speedup 1.0000x reference)
//
#include <hip/hip_runtime.h>

#define NB 4
#define CC 512
#define NSP 4096
#define NGRP 32

using bf16x8 = __attribute__((ext_vector_type(8))) __bf16;
using f32x4  = __attribute__((ext_vector_type(4))) float;

__device__ __forceinline__ unsigned short f2bf(float f) {
  union { float f; unsigned int u; } v; v.f = f;
  unsigned int r = v.u + 0x7fffu + ((v.u >> 16) & 1u);
  return (unsigned short)(r >> 16);
}
__device__ __forceinline__ float bf2f(unsigned short h) {
  union { unsigned int u; float f; } v; v.u = ((unsigned int)h) << 16;
  return v.f;
}

// ---------------- weight fp32 -> bf16 ----------------
__global__ __launch_bounds__(256) void cvt_w_kernel(const float* __restrict__ wq,
    const float* __restrict__ wk, const float* __restrict__ wv,
    const float* __restrict__ wo, unsigned short* __restrict__ out) {
  int i = blockIdx.x * 256 + threadIdx.x;
  out[i]          = f2bf(wq[i]);
  out[i + 262144] = f2bf(wk[i]);
  out[i + 524288] = f2bf(wv[i]);
  out[i + 786432] = f2bf(wo[i]);
}

// ---------------- GroupNorm stats ----------------
__global__ __launch_bounds__(256) void gn_stats_kernel(const float* __restrict__ x,
                                                       float* __restrict__ stats) {
  const int b = blockIdx.x >> 5, g = blockIdx.x & 31;
  const float4* p = reinterpret_cast<const float4*>(x + ((size_t)b * CC + g * 16) * NSP);
  float s = 0.f, ss = 0.f;
  for (int i = threadIdx.x; i < 16384; i += 256) {
    float4 v = p[i];
    s  += v.x + v.y + v.z + v.w;
    ss += v.x * v.x + v.y * v.y + v.z * v.z + v.w * v.w;
  }
  __shared__ float rs[4], rss[4];
  #pragma unroll
  for (int o = 32; o >= 1; o >>= 1) { s += __shfl_down(s, o); ss += __shfl_down(ss, o); }
  if ((threadIdx.x & 63) == 0) { rs[threadIdx.x >> 6] = s; rss[threadIdx.x >> 6] = ss; }
  __syncthreads();
  if (threadIdx.x == 0) {
    s = rs[0] + rs[1] + rs[2] + rs[3];
    ss = rss[0] + rss[1] + rss[2] + rss[3];
    float mean = s * (1.f / 65536.f);
    float var = ss * (1.f / 65536.f) - mean * mean;
    stats[blockIdx.x * 2 + 0] = mean;
    stats[blockIdx.x * 2 + 1] = rsqrtf(var + 1e-6f);
  }
}

// ---------------- GN apply + transpose to xnT [B][N][C] bf16 ----------------
__global__ __launch_bounds__(256) void gn_apply_kernel(const float* __restrict__ x,
    const float* __restrict__ stats, const float* __restrict__ gw,
    const float* __restrict__ gb, unsigned short* __restrict__ xnT) {
  const int b = blockIdx.z, c0 = blockIdx.y * 32, n0 = blockIdx.x * 32;
  __shared__ unsigned short tile[32][33];
  const int tx = threadIdx.x & 31, ty = threadIdx.x >> 5;
  #pragma unroll
  for (int r = 0; r < 4; ++r) {
    const int cl = ty + r * 8;
    const int c = c0 + cl;
    const int g = c >> 4;
    const float mean = stats[(b * 32 + g) * 2];
    const float rstd = stats[(b * 32 + g) * 2 + 1];
    const float sc = rstd * gw[c];
    const float sh = gb[c] - mean * sc;
    const float v = x[((size_t)b * CC + c) * NSP + n0 + tx];
    tile[cl][tx] = f2bf(v * sc + sh);
  }
  __syncthreads();
  #pragma unroll
  for (int r = 0; r < 4; ++r) {
    const int nl = ty + r * 8;
    xnT[((size_t)b * NSP + n0 + nl) * CC + c0 + tx] = tile[tx][nl];
  }
}

// ---------------- sum 64 partials -> 1/l per row ----------------
__global__ __launch_bounds__(256) void sum_reduce_kernel(const float* __restrict__ part,
                                                         float* __restrict__ invl) {
  const int row = blockIdx.x * 4 + (threadIdx.x >> 6);
  const int lane = threadIdx.x & 63;
  float v = part[((size_t)row << 6) + lane];
  #pragma unroll
  for (int msk = 1; msk <= 32; msk <<= 1) v += __shfl_xor(v, msk);
  if (lane == 0) invl[row] = 1.f / v;
}

// ---------------- 128^2 MFMA GEMM (small GEMMs: qkv / proj) ----------------
template<int BIAS, bool OBF16, bool RESID>
__global__ __launch_bounds__(256) void gemm2(
    const unsigned short* __restrict__ A, const unsigned short* __restrict__ B,
    const float* __restrict__ bias, const float* __restrict__ resid,
    void* __restrict__ Cout, int M, int N, int K, float scale,
    long long sAb, long long sBb, long long sCb, long long sRb) {
  __shared__ __align__(16) unsigned short sA[2][128 * 64];
  __shared__ __align__(16) unsigned short sB[2][128 * 64];
  const int tid = threadIdx.x;
  const int lane = tid & 63;
  const int wid  = tid >> 6;

  const unsigned nwg = gridDim.x * gridDim.y * gridDim.z;
  unsigned lin = blockIdx.x + gridDim.x * (blockIdx.y + gridDim.y * blockIdx.z);
  lin = (lin & 7) * (nwg >> 3) + (lin >> 3);
  const int bn = lin % gridDim.x;
  const unsigned t2 = lin / gridDim.x;
  const int bm = t2 % gridDim.y;
  const int b  = t2 / gridDim.y;

  const unsigned short* Ab = A + (size_t)b * sAb + (size_t)bm * 128 * K;
  const unsigned short* Bb = B + (size_t)b * sBb + (size_t)bn * 128 * K;
  const int wm = wid >> 1, wn = wid & 1;
  const int l15 = lane & 15, h = lane >> 4;

  f32x4 acc[4][4] = {};

  auto stage = [&](int buf, int k0) {
    #pragma unroll
    for (int it = 0; it < 4; ++it) {
      const int o  = (it * 256 + tid) * 16;
      const int r  = o >> 7;
      const int c2 = (o & 127) ^ ((r & 7) << 4);
      __builtin_amdgcn_global_load_lds(
          (const __attribute__((address_space(1))) void*)((const char*)(Ab + (size_t)r * K + k0) + c2),
          (__attribute__((address_space(3))) void*)((char*)sA[buf] + o), 16, 0, 0);
      __builtin_amdgcn_global_load_lds(
          (const __attribute__((address_space(1))) void*)((const char*)(Bb + (size_t)r * K + k0) + c2),
          (__attribute__((address_space(3))) void*)((char*)sB[buf] + o), 16, 0, 0);
    }
  };

  int abase[4], bbase[4];
  #pragma unroll
  for (int i = 0; i < 4; ++i) {
    const int ar = wm * 64 + i * 16 + l15;
    abase[i] = ar * 128 + (((ar & 7) << 4) ^ (h << 4));
    const int br = wn * 64 + i * 16 + l15;
    bbase[i] = br * 128 + (((br & 7) << 4) ^ (h << 4));
  }

  stage(0, 0);
  const int NT = K >> 6;
  #pragma unroll 1
  for (int t = 0; t < NT; ++t) {
    const int cur = t & 1;
    if (t + 1 < NT) {
      stage(cur ^ 1, (t + 1) << 6);
      asm volatile("s_waitcnt vmcnt(8)" ::: "memory");
    } else {
      asm volatile("s_waitcnt vmcnt(0)" ::: "memory");
    }
    __builtin_amdgcn_sched_barrier(0);
    __builtin_amdgcn_s_barrier();
    __builtin_amdgcn_sched_barrier(0);

    const char* cA = (const char*)sA[cur];
    const char* cB = (const char*)sB[cur];
    #pragma unroll
    for (int kk = 0; kk < 2; ++kk) {
      bf16x8 af[4], bfr[4];
      #pragma unroll
      for (int m = 0; m < 4; ++m)
        af[m] = *reinterpret_cast<const bf16x8*>(cA + (abase[m] ^ (kk << 6)));
      #pragma unroll
      for (int n = 0; n < 4; ++n)
        bfr[n] = *reinterpret_cast<const bf16x8*>(cB + (bbase[n] ^ (kk << 6)));
      #pragma unroll
      for (int m = 0; m < 4; ++m)
        #pragma unroll
        for (int n = 0; n < 4; ++n)
          acc[m][n] = __builtin_amdgcn_mfma_f32_16x16x32_bf16(af[m], bfr[n], acc[m][n], 0, 0, 0);
    }
    __builtin_amdgcn_sched_barrier(0);
    __builtin_amdgcn_s_barrier();
    __builtin_amdgcn_sched_barrier(0);
  }

  float* outf = (float*)Cout;
  unsigned short* outh = (unsigned short*)Cout;
  const size_t cb = (size_t)b * sCb;
  #pragma unroll
  for (int m = 0; m < 4; ++m) {
    #pragma unroll
    for (int r = 0; r < 4; ++r) {
      const int row = bm * 128 + wm * 64 + m * 16 + h * 4 + r;
      #pragma unroll
      for (int n = 0; n < 4; ++n) {
        const int col = bn * 128 + wn * 64 + n * 16 + l15;
        float vv = acc[m][n][r];
        if constexpr (BIAS == 1) vv += bias[row];
        if constexpr (BIAS == 2) vv += bias[col];
        vv *= scale;
        if constexpr (RESID) vv += resid[(size_t)b * sRb + (size_t)row * N + col];
        const size_t oi = cb + (size_t)row * N + col;
        if constexpr (OBF16) outh[oi] = f2bf(vv);
        else outf[oi] = vv;
      }
    }
  }
}

// ---------------- 8-wave phase-split MFMA GEMM (big attention GEMMs) ----------------
// 512 threads, waves 2D (WMS x WNS), per-wave (BM/WMS) x 64 output, BK=64.
// Per K-tile: burst-stage next tile -> counted vmcnt -> barrier -> M_rep/2 phases of
// {ds_read frags; lgkmcnt(0); setprio(1); 16 MFMA; setprio(0); barrier}.
// EXPOUT: C = exp(min(acc*scale,80)) bf16 + per-row 64-col partial sums.
// INVL:   C = acc * invl_in[row] bf16.
template<int BM, int BN, int WMS, int WNS, bool EXPOUT, bool INVL>
__global__ __launch_bounds__(512) void gemm8(
    const unsigned short* __restrict__ A, const unsigned short* __restrict__ B,
    void* __restrict__ Cout, const float* __restrict__ invl_in,
    float* __restrict__ part_out, int N, int K, float scale,
    long long sAb, long long sBb, long long sCb) {
  constexpr int WR = BM / WMS;          // wave rows
  constexpr int M_REP = WR / 16;        // 8 (256x256) or 4 (256x128)
  constexpr int LOADS = BM / 64 + BN / 64;
  __shared__ __align__(16) unsigned short sA[2][BM * 64];
  __shared__ __align__(16) unsigned short sB[2][BN * 64];
  const int tid = threadIdx.x;
  const int lane = tid & 63;
  const int wid  = tid >> 6;

  const unsigned nwg = gridDim.x * gridDim.y * gridDim.z;
  unsigned lin = blockIdx.x + gridDim.x * (blockIdx.y + gridDim.y * blockIdx.z);
  lin = (lin & 7) * (nwg >> 3) + (lin >> 3);
  const int bn = lin % gridDim.x;
  const unsigned t2 = lin / gridDim.x;
  const int bm = t2 % gridDim.y;
  const int b  = t2 / gridDim.y;

  const unsigned short* Ab = A + (size_t)b * sAb + (size_t)bm * BM * K;
  const unsigned short* Bb = B + (size_t)b * sBb + (size_t)bn * BN * K;
  const int wm = wid / WNS, wn = wid % WNS;
  const int l15 = lane & 15, h = lane >> 4;

  f32x4 acc[M_REP][4] = {};

  auto stage = [&](int buf, int k0) {
    #pragma unroll
    for (int it = 0; it < BM / 64; ++it) {
      const int o  = (it * 512 + tid) * 16;
      const int r  = o >> 7;
      const int c2 = (o & 127) ^ ((r & 7) << 4);
      __builtin_amdgcn_global_load_lds(
          (const __attribute__((address_space(1))) void*)((const char*)(Ab + (size_t)r * K + k0) + c2),
          (__attribute__((address_space(3))) void*)((char*)sA[buf] + o), 16, 0, 0);
    }
    #pragma unroll
    for (int it = 0; it < BN / 64; ++it) {
      const int o  = (it * 512 + tid) * 16;
      const int r  = o >> 7;
      const int c2 = (o & 127) ^ ((r & 7) << 4);
      __builtin_amdgcn_global_load_lds(
          (const __attribute__((address_space(1))) void*)((const char*)(Bb + (size_t)r * K + k0) + c2),
          (__attribute__((address_space(3))) void*)((char*)sB[buf] + o), 16, 0, 0);
    }
  };

  int abase[M_REP], bbase[4];
  #pragma unroll
  for (int i = 0; i < M_REP; ++i) {
    const int ar = wm * WR + i * 16 + l15;
    abase[i] = ar * 128 + (((ar & 7) << 4) ^ (h << 4));
  }
  #pragma unroll
  for (int i = 0; i < 4; ++i) {
    const int br = wn * 64 + i * 16 + l15;
    bbase[i] = br * 128 + (((br & 7) << 4) ^ (h << 4));
  }

  stage(0, 0);
  const int NT = K >> 6;
  #pragma unroll 1
  for (int t = 0; t < NT; ++t) {
    const int cur = t & 1;
    if (t + 1 < NT) {
      stage(cur ^ 1, (t + 1) << 6);
      if constexpr (LOADS == 8) asm volatile("s_waitcnt vmcnt(8)" ::: "memory");
      else                      asm volatile("s_waitcnt vmcnt(6)" ::: "memory");
    } else {
      asm volatile("s_waitcnt vmcnt(0)" ::: "memory");
    }
    __builtin_amdgcn_sched_barrier(0);
    __builtin_amdgcn_s_barrier();
    __builtin_amdgcn_sched_barrier(0);

    const char* cA = (const char*)sA[cur];
    const char* cB = (const char*)sB[cur];

    // B-frags for the whole tile (8 ds_read_b128), reused across phases
    bf16x8 bfr[2][4];
    #pragma unroll
    for (int kk = 0; kk < 2; ++kk)
      #pragma unroll
      for (int n = 0; n < 4; ++n)
        bfr[kk][n] = *reinterpret_cast<const bf16x8*>(cB + (bbase[n] ^ (kk << 6)));

    #pragma unroll
    for (int p = 0; p < M_REP / 2; ++p) {
      bf16x8 af[2][2];
      #pragma unroll
      for (int i = 0; i < 2; ++i)
        #pragma unroll
        for (int kk = 0; kk < 2; ++kk)
          af[kk][i] = *reinterpret_cast<const bf16x8*>(cA + (abase[2 * p + i] ^ (kk << 6)));
      asm volatile("s_waitcnt lgkmcnt(0)" ::: "memory");
      __builtin_amdgcn_sched_barrier(0);
      __builtin_amdgcn_s_setprio(1);
      #pragma unroll
      for (int i = 0; i < 2; ++i)
        #pragma unroll
        for (int n = 0; n < 4; ++n)
          #pragma unroll
          for (int kk = 0; kk < 2; ++kk)
            acc[2 * p + i][n] =
                __builtin_amdgcn_mfma_f32_16x16x32_bf16(af[kk][i], bfr[kk][n], acc[2 * p + i][n], 0, 0, 0);
      __builtin_amdgcn_s_setprio(0);
      __builtin_amdgcn_sched_barrier(0);
      __builtin_amdgcn_s_barrier();
      __builtin_amdgcn_sched_barrier(0);
    }
  }

  unsigned short* outh = (unsigned short*)Cout;
  const size_t cb = (size_t)b * sCb;
  #pragma unroll
  for (int m = 0; m < M_REP; ++m) {
    #pragma unroll
    for (int r = 0; r < 4; ++r) {
      const int row = bm * BM + wm * WR + m * 16 + h * 4 + r;
      if constexpr (EXPOUT) {
        float se = 0.f;
        #pragma unroll
        for (int n = 0; n < 4; ++n) {
          const int col = bn * BN + wn * 64 + n * 16 + l15;
          unsigned short pb = f2bf(__expf(fminf(acc[m][n][r] * scale, 80.f)));
          outh[cb + (size_t)row * N + col] = pb;
          se += bf2f(pb);
        }
        #pragma unroll
        for (int msk = 1; msk <= 8; msk <<= 1) se += __shfl_xor(se, msk);
        if (l15 == 0)
          part_out[(((size_t)b * NSP + row) << 6) + bn * (BN / 64) + wn] = se;
      } else {
        float invl = 1.0f;
        if constexpr (INVL) invl = invl_in[(size_t)b * NSP + row];
        #pragma unroll
        for (int n = 0; n < 4; ++n) {
          const int col = bn * BN + wn * 64 + n * 16 + l15;
          outh[cb + (size_t)row * N + col] = f2bf(acc[m][n][r] * scale * invl);
        }
      }
    }
  }
}

extern "C" void kernel_launch(void* const* d_in, const int* in_sizes, int n_in,
                              void* d_out, int out_size, void* d_ws, size_t ws_size,
                              hipStream_t stream) {
  const float* x    = (const float*)d_in[0];
  const float* gn_w = (const float*)d_in[1];
  const float* gn_b = (const float*)d_in[2];
  const float* wq   = (const float*)d_in[3];
  const float* bq   = (const float*)d_in[4];
  const float* wk   = (const float*)d_in[5];
  const float* bk   = (const float*)d_in[6];
  const float* wv   = (const float*)d_in[7];
  const float* bv   = (const float*)d_in[8];
  const float* wo   = (const float*)d_in[9];
  const float* bo   = (const float*)d_in[10];
  float* out = (float*)d_out;

  char* ws = (char*)d_ws;
  const size_t NC = (size_t)NSP * CC;
  unsigned short* wq_bf = (unsigned short*)ws;
  unsigned short* wk_bf = wq_bf + 262144;
  unsigned short* wv_bf = wq_bf + 524288;
  unsigned short* wo_bf = wq_bf + 786432;
  unsigned short* xnT   = wq_bf + 1048576;          // [B][N][C]
  unsigned short* qT    = xnT + NB * NC;            // [B][N][C] pre-scaled
  unsigned short* kT    = qT + NB * NC;
  unsigned short* vC    = kT + NB * NC;             // [B][C][N]
  unsigned short* aoutT = vC + NB * NC;             // [B][N][C]
  float* gstats = (float*)(aoutT + NB * NC);
  unsigned short* S = (unsigned short*)((char*)gstats + 1024);   // [B][N][N] bf16 P_unnorm
  float* part = (float*)(S + (size_t)NB * NSP * NSP);            // [B*N][64]
  float* invl = part + ((size_t)NB * NSP << 6);                  // [B*N]

  const float scale = 0.04419417382415922f;  // 512^-0.5
  const size_t SS = (size_t)NSP * NSP;

  cvt_w_kernel<<<1024, 256, 0, stream>>>(wq, wk, wv, wo, wq_bf);
  gn_stats_kernel<<<NB * NGRP, 256, 0, stream>>>(x, gstats);
  gn_apply_kernel<<<dim3(NSP / 32, CC / 32, NB), 256, 0, stream>>>(x, gstats, gn_w, gn_b, xnT);

  // qT = (xnT.wq^T + bq)*scale ; kT = xnT.wk^T + bk
  gemm2<2, true, false><<<dim3(CC / 128, NSP / 128, NB), 256, 0, stream>>>(
      xnT, wq_bf, bq, nullptr, qT, NSP, CC, CC, scale, NC, 0, NC, 0);
  gemm2<2, true, false><<<dim3(CC / 128, NSP / 128, NB), 256, 0, stream>>>(
      xnT, wk_bf, bk, nullptr, kT, NSP, CC, CC, 1.0f, NC, 0, NC, 0);
  // vC[o,i] = wv.xnT^T + bv
  gemm2<1, true, false><<<dim3(NSP / 128, CC / 128, NB), 256, 0, stream>>>(
      wv_bf, xnT, bv, nullptr, vC, CC, NSP, CC, 1.0f, 0, NC, NC, 0);

  // P_unnorm = exp(qT.kT^T) bf16 + per-row partial sums (256x256 8-wave phase-split)
  gemm8<256, 256, 2, 4, true, false><<<dim3(NSP / 256, NSP / 256, NB), 512, 0, stream>>>(
      qT, kT, S, nullptr, part, NSP, CC, 1.0f, NC, NC, (long long)SS);
  sum_reduce_kernel<<<NB * NSP / 4, 256, 0, stream>>>(part, invl);
  // aoutT = (P_unnorm . V) * (1/l)   (256x128 8-wave phase-split, grid = 256 WGs)
  gemm8<256, 128, 4, 2, false, true><<<dim3(CC / 128, NSP / 256, NB), 512, 0, stream>>>(
      S, vC, aoutT, invl, nullptr, CC, NSP, 1.0f, SS, NC, NC);

  // out = wo.aoutT^T + bo + x
  gemm2<1, false, true><<<dim3(NSP / 128, CC / 128, NB), 256, 0, stream>>>(
      wo_bf, aoutT, bo, x, out, CC, NSP, CC, 1.0f, 0, NC, NC, NC);
}